// Round 1
// baseline (7498.573 us; speedup 1.0000x reference)
//
#include <hip/hip_runtime.h>
#include <cstdint>
#include <cstddef>

#define F4(p)  (*(reinterpret_cast<float4*>(p)))
#define CF4(p) (*(reinterpret_cast<const float4*>(p)))

// =====================================================================
// Generic fp32 GEMM:  C[M,N] = relu?( scale * (A @ B^T) + bias + src )
//   A: M x K (lda), B: N x K (ldb), C: M x N (ldc)
//   Requires M%64==0, N%64==0, K%32==0 (all shapes in this problem comply)
// 64x64 tile, 256 threads, 4x4 micro-tile, k-major LDS (vector ds_read_b128)
// =====================================================================
__global__ __launch_bounds__(256) void gemm_nt(
    const float* __restrict__ A, int lda,
    const float* __restrict__ B, int ldb,
    float* __restrict__ C, int ldc,
    int K,
    const float* __restrict__ bias,
    const float* __restrict__ src, int ldsrc,
    const float* __restrict__ scale_ptr,
    int relu)
{
  __shared__ float As[32][64];
  __shared__ float Bs[32][64];
  const int tid = threadIdx.x;
  const int gm0 = blockIdx.y * 64;
  const int gn0 = blockIdx.x * 64;
  const int tr = (tid >> 4) << 2;   // row offset 0..60
  const int tc = (tid & 15) << 2;   // col offset 0..60
  float acc[4][4] = {};

  const float* Ab = A + (size_t)gm0 * lda;
  const float* Bb = B + (size_t)gn0 * ldb;

  for (int kk = 0; kk < K; kk += 32) {
    #pragma unroll
    for (int l = 0; l < 2; ++l) {
      int idx = tid + l * 256;          // 0..511
      int m  = idx >> 3;                // 0..63
      int k4 = (idx & 7) << 2;          // 0..28
      float4 a4 = CF4(Ab + (size_t)m * lda + kk + k4);
      As[k4+0][m] = a4.x; As[k4+1][m] = a4.y; As[k4+2][m] = a4.z; As[k4+3][m] = a4.w;
      float4 b4 = CF4(Bb + (size_t)m * ldb + kk + k4);
      Bs[k4+0][m] = b4.x; Bs[k4+1][m] = b4.y; Bs[k4+2][m] = b4.z; Bs[k4+3][m] = b4.w;
    }
    __syncthreads();
    #pragma unroll
    for (int k = 0; k < 32; ++k) {
      float4 a = CF4(&As[k][tr]);
      float4 b = CF4(&Bs[k][tc]);
      acc[0][0] += a.x*b.x; acc[0][1] += a.x*b.y; acc[0][2] += a.x*b.z; acc[0][3] += a.x*b.w;
      acc[1][0] += a.y*b.x; acc[1][1] += a.y*b.y; acc[1][2] += a.y*b.z; acc[1][3] += a.y*b.w;
      acc[2][0] += a.z*b.x; acc[2][1] += a.z*b.y; acc[2][2] += a.z*b.z; acc[2][3] += a.z*b.w;
      acc[3][0] += a.w*b.x; acc[3][1] += a.w*b.y; acc[3][2] += a.w*b.z; acc[3][3] += a.w*b.w;
    }
    __syncthreads();
  }

  float sc = 1.0f;
  if (scale_ptr) sc = *scale_ptr;
  float b0 = 0.f, b1 = 0.f, b2 = 0.f, b3 = 0.f;
  if (bias) {
    float4 bb = CF4(bias + gn0 + tc);
    b0 = bb.x; b1 = bb.y; b2 = bb.z; b3 = bb.w;
  }
  #pragma unroll
  for (int i = 0; i < 4; ++i) {
    size_t row = (size_t)(gm0 + tr + i);
    float o0 = acc[i][0]*sc + b0;
    float o1 = acc[i][1]*sc + b1;
    float o2 = acc[i][2]*sc + b2;
    float o3 = acc[i][3]*sc + b3;
    if (src) {
      float4 s4 = CF4(src + row * ldsrc + gn0 + tc);
      o0 += s4.x; o1 += s4.y; o2 += s4.z; o3 += s4.w;
    }
    if (relu) {
      o0 = fmaxf(o0, 0.f); o1 = fmaxf(o1, 0.f);
      o2 = fmaxf(o2, 0.f); o3 = fmaxf(o3, 0.f);
    }
    float4 ov; ov.x = o0; ov.y = o1; ov.z = o2; ov.w = o3;
    F4(C + row * ldc + gn0 + tc) = ov;
  }
}

// =====================================================================
// Transpose: in (R x Cc submatrix, leading dim ldin) -> out (Cc x R, ld R)
// =====================================================================
__global__ __launch_bounds__(256) void transpose_k(
    const float* __restrict__ in, int ldin, float* __restrict__ outp, int R)
{
  __shared__ float tile[32][33];
  int c0 = blockIdx.x * 32, r0 = blockIdx.y * 32;
  int tx = threadIdx.x & 31, ty = threadIdx.x >> 5;
  #pragma unroll
  for (int i = ty; i < 32; i += 8)
    tile[i][tx] = in[(size_t)(r0 + i) * ldin + c0 + tx];
  __syncthreads();
  #pragma unroll
  for (int i = ty; i < 32; i += 8)
    outp[(size_t)(c0 + i) * R + r0 + tx] = tile[tx][i];
}

// =====================================================================
// matvec: out[i] = dot(A[i,:K], x) + badd[i]   (grid = #rows, 64 threads)
// =====================================================================
__global__ __launch_bounds__(64) void matvec_nt(
    const float* __restrict__ A, int lda,
    const float* __restrict__ x,
    const float* __restrict__ badd,
    float* __restrict__ outp, int K)
{
  int i = blockIdx.x, t = threadIdx.x;
  const float* Ar = A + (size_t)i * lda;
  float s = 0.f;
  for (int k = t * 4; k < K; k += 256) {
    float4 a = CF4(Ar + k);
    float4 xx = CF4(x + k);
    s += a.x*xx.x + a.y*xx.y + a.z*xx.z + a.w*xx.w;
  }
  #pragma unroll
  for (int m = 32; m > 0; m >>= 1) s += __shfl_xor(s, m);
  if (t == 0) outp[i] = s + (badd ? badd[i] : 0.f);
}

// =====================================================================
// importance softmax + rep vector (rep[m*1024+g] = imp[m]*attn_out_b[g])
// =====================================================================
__global__ __launch_bounds__(256) void imp_rep_k(
    const float* __restrict__ importance, const float* __restrict__ aob,
    float* __restrict__ imp, float* __restrict__ rep)
{
  __shared__ float si[3];
  if (threadIdx.x == 0) {
    float a = importance[0], b = importance[1], c = importance[2];
    float mx = fmaxf(a, fmaxf(b, c));
    float ea = expf(a - mx), eb = expf(b - mx), ec = expf(c - mx);
    float inv = 1.f / (ea + eb + ec);
    si[0] = ea * inv; si[1] = eb * inv; si[2] = ec * inv;
    imp[0] = si[0]; imp[1] = si[1]; imp[2] = si[2];
  }
  __syncthreads();
  for (int idx = threadIdx.x; idx < 3072; idx += 256)
    rep[idx] = si[idx >> 10] * aob[idx & 1023];
}

// =====================================================================
// 3-token multihead attention (8 heads x 128): per-block one sample n.
// qkv row layout per n: token m in [0,3): [q(1024) | k(1024) | v(1024)]
// writes att (n, 3*1024) = softmax(qk^T/sqrt(128)) @ v, flattened (N,3072)
// =====================================================================
__global__ __launch_bounds__(256) void attn3(
    const float* __restrict__ qkv, float* __restrict__ att)
{
  const int n = blockIdx.x;
  const float* row = qkv + (size_t)n * 9216;
  __shared__ float qk[6144];
  __shared__ float sc[72];
  __shared__ float pw[72];
  const int t = threadIdx.x;
  for (int idx = t; idx < 1536; idx += 256) {
    int m = idx >> 8;                 // 0..5 (0..2 = q of token m, 3..5 = k)
    int off = (idx & 255) << 2;
    const float* srcp = (m < 3) ? (row + m * 3072 + off)
                                : (row + (m - 3) * 3072 + 1024 + off);
    F4(&qk[m * 1024 + off]) = CF4(srcp);
  }
  __syncthreads();
  if (t < 72) {                        // t = h*9 + i*3 + j
    int h = t / 9, i = (t % 9) / 3, j = t % 3;
    const float* qp = &qk[i * 1024 + h * 128];
    const float* kp = &qk[3072 + j * 1024 + h * 128];
    float s = 0.f;
    int rot = (t & 31) * 4;            // skew to spread LDS banks
    for (int d2 = 0; d2 < 128; ++d2) {
      int dx = (d2 + rot) & 127;
      s += qp[dx] * kp[dx];
    }
    sc[t] = s * 0.08838834764831845f;  // 1/sqrt(128)
  }
  __syncthreads();
  if (t < 24) {                        // t = h*3 + i
    int base = t * 3;
    float a = sc[base], b = sc[base + 1], c = sc[base + 2];
    float mx = fmaxf(a, fmaxf(b, c));
    float ea = expf(a - mx), eb = expf(b - mx), ec = expf(c - mx);
    float inv = 1.f / (ea + eb + ec);
    pw[base] = ea * inv; pw[base + 1] = eb * inv; pw[base + 2] = ec * inv;
  }
  __syncthreads();
  float* outp = att + (size_t)n * 3072;
  #pragma unroll
  for (int rep = 0; rep < 3; ++rep) {
    int idx = (rep * 256 + t) << 2;    // 0..3068
    int i  = idx >> 10;
    int hd = idx & 1023;
    int h  = hd >> 7;
    int pb = (h * 3 + i) * 3;
    float w0 = pw[pb], w1 = pw[pb + 1], w2 = pw[pb + 2];
    float4 v0 = CF4(row + 2048 + hd);
    float4 v1 = CF4(row + 3072 + 2048 + hd);
    float4 v2 = CF4(row + 6144 + 2048 + hd);
    float4 o;
    o.x = w0*v0.x + w1*v1.x + w2*v2.x;
    o.y = w0*v0.y + w1*v1.y + w2*v2.y;
    o.z = w0*v0.z + w1*v1.z + w2*v2.z;
    o.w = w0*v0.w + w1*v1.w + w2*v2.w;
    F4(outp + idx) = o;
  }
}

// =====================================================================
// Row LayerNorm in-place (rows of 1024), jnp.var semantics (ddof=0)
// =====================================================================
__global__ __launch_bounds__(256) void layernorm_ip(
    float* __restrict__ X, const float* __restrict__ g, const float* __restrict__ bta)
{
  int n = blockIdx.x, t = threadIdx.x;
  float* row = X + (size_t)n * 1024;
  float4 v = CF4(row + t * 4);
  float s  = v.x + v.y + v.z + v.w;
  float ss = v.x*v.x + v.y*v.y + v.z*v.z + v.w*v.w;
  #pragma unroll
  for (int m = 32; m > 0; m >>= 1) { s += __shfl_xor(s, m); ss += __shfl_xor(ss, m); }
  __shared__ float rs[4], rss[4];
  int w = t >> 6;
  if ((t & 63) == 0) { rs[w] = s; rss[w] = ss; }
  __syncthreads();
  s  = rs[0] + rs[1] + rs[2] + rs[3];
  ss = rss[0] + rss[1] + rss[2] + rss[3];
  float mean = s * (1.0f / 1024.0f);
  float var  = ss * (1.0f / 1024.0f) - mean * mean;
  float inv  = 1.0f / sqrtf(var + 1e-5f);
  float4 gg = CF4(g + t * 4);
  float4 bb = CF4(bta + t * 4);
  float4 o;
  o.x = (v.x - mean) * inv * gg.x + bb.x;
  o.y = (v.y - mean) * inv * gg.y + bb.y;
  o.z = (v.z - mean) * inv * gg.z + bb.z;
  o.w = (v.w - mean) * inv * gg.w + bb.w;
  F4(row + t * 4) = o;
}

// =====================================================================
// R[b*128+t] = (t==0) ? s0[b] : F_post_b[b*128+t-1] + noise[b*128+t-1]
// =====================================================================
__global__ __launch_bounds__(256) void build_R_k(
    const float* __restrict__ Fpb, const float* __restrict__ noise,
    const float* __restrict__ s0, float* __restrict__ R)
{
  size_t idx = (size_t)blockIdx.x * 256 + threadIdx.x;   // < 8192*256
  int n = (int)(idx >> 8);
  int k4 = (int)(idx & 255) << 2;
  float4 v;
  if ((n & 127) == 0) {
    v = CF4(s0 + (size_t)(n >> 7) * 1024 + k4);
  } else {
    float4 f = CF4(Fpb + (size_t)(n - 1) * 1024 + k4);
    float4 z = CF4(noise + (size_t)(n - 1) * 1024 + k4);
    v.x = f.x + z.x; v.y = f.y + z.y; v.z = f.z + z.z; v.w = f.w + z.w;
  }
  F4(R + (size_t)n * 1024 + k4) = v;
}

// =====================================================================
// s_new = post + noise  (post already in out cols [2304,3328))
// =====================================================================
__global__ __launch_bounds__(256) void s_out_k(
    float* __restrict__ outp, const float* __restrict__ noise)
{
  size_t idx = (size_t)blockIdx.x * 256 + threadIdx.x;
  int n = (int)(idx >> 8);
  int j4 = (int)(idx & 255) << 2;
  float4 p = CF4(outp + (size_t)n * 3328 + 2304 + j4);
  float4 z = CF4(noise + (size_t)n * 1024 + j4);
  float4 o; o.x = p.x + z.x; o.y = p.y + z.y; o.z = p.z + z.z; o.w = p.w + z.w;
  F4(outp + (size_t)n * 3328 + 256 + j4) = o;
}

// =====================================================================
// h0 -> hglob buf0, transposed layout hglob[d*64 + b]
// =====================================================================
__global__ __launch_bounds__(256) void copy_h0_k(
    const float* __restrict__ h0, float* __restrict__ hglob)
{
  int idx = blockIdx.x * 256 + threadIdx.x;   // < 16384
  hglob[(idx & 255) * 64 + (idx >> 8)] = h0[idx];
}

// =====================================================================
// Sequential RSSM rollout. 64 blocks = 4 b-chunks(16 b) x 16 d-chunks(16 d);
// 256 threads = 16 bl x 16 dl. Per step:
//   gi = (t>0)*h_t@M1^T + Q[t];  gh = h_t@Whh^T + b_hh;  GRU -> h_{t+1}
// h exchanged via hglob ping-pong + device-scope atomic counter barrier.
// Weights streamed LDS-quarterwise from L2 (M1 768x256 in ws, Whh input).
// All 64 blocks co-resident (LDS 42.5KB, 256 thr) => barrier is safe.
// =====================================================================
__global__ __launch_bounds__(256) void rssm_recur(
    const float* __restrict__ M1, const float* __restrict__ Whh,
    const float* __restrict__ bhh, const float* __restrict__ Q,
    float* __restrict__ hglob, float* __restrict__ out,
    unsigned int* __restrict__ counter)
{
  const int bb = blockIdx.x >> 4;    // 0..3
  const int dd = blockIdx.x & 15;    // 0..15
  const int tid = threadIdx.x;
  const int bl = tid & 15, dl = tid >> 4;
  const int b = bb * 16 + bl;
  const int d = dd * 16 + dl;
  __shared__ float hl[256][16];      // h[k][b_local]
  __shared__ float wq[6][16][68];    // 6 row-groups x 16 rows x 64k (+4 pad)

  const float bh0 = bhh[d], bh1 = bhh[256 + d], bh2 = bhh[512 + d];
  unsigned int target = 0;

  for (int t = 0; t < 128; ++t) {
    // stage h_t (full 256 x 16 local-b slice)
    const float* hsrc = hglob + (size_t)(t & 1) * 16384 + bb * 16;
    for (int idx = tid; idx < 4096; idx += 256)
      hl[idx >> 4][idx & 15] = hsrc[(size_t)(idx >> 4) * 64 + (idx & 15)];

    float acc0 = 0.f, acc1 = 0.f, acc2 = 0.f, acc3 = 0.f, acc4 = 0.f, acc5 = 0.f;
    for (int q = 0; q < 4; ++q) {
      __syncthreads();   // hl staged (q==0) / previous quarter consumed
      for (int idx = tid; idx < 1536; idx += 256) {
        int r = idx >> 4;             // 0..95
        int c = r >> 4, j = r & 15;   // row-group, row-in-group
        int kq = (idx & 15) << 2;     // 0..60
        const float* srcp = (c < 3)
            ? (M1 + (size_t)((c << 8) + dd * 16 + j) * 256 + (q << 6) + kq)
            : (Whh + (size_t)(((c - 3) << 8) + dd * 16 + j) * 256 + (q << 6) + kq);
        float4 w4 = CF4(srcp);
        float* dst = &wq[c][j][kq];
        dst[0] = w4.x; dst[1] = w4.y; dst[2] = w4.z; dst[3] = w4.w;
      }
      __syncthreads();
      #pragma unroll
      for (int k2 = 0; k2 < 64; k2 += 4) {
        const int k = (q << 6) + k2;
        const float h0v = hl[k][bl], h1v = hl[k + 1][bl];
        const float h2v = hl[k + 2][bl], h3v = hl[k + 3][bl];
        float4 w0 = CF4(&wq[0][dl][k2]);
        float4 w1 = CF4(&wq[1][dl][k2]);
        float4 w2 = CF4(&wq[2][dl][k2]);
        float4 w3 = CF4(&wq[3][dl][k2]);
        float4 w4v = CF4(&wq[4][dl][k2]);
        float4 w5 = CF4(&wq[5][dl][k2]);
        acc0 += w0.x*h0v + w0.y*h1v + w0.z*h2v + w0.w*h3v;
        acc1 += w1.x*h0v + w1.y*h1v + w1.z*h2v + w1.w*h3v;
        acc2 += w2.x*h0v + w2.y*h1v + w2.z*h2v + w2.w*h3v;
        acc3 += w3.x*h0v + w3.y*h1v + w3.z*h2v + w3.w*h3v;
        acc4 += w4v.x*h0v + w4v.y*h1v + w4v.z*h2v + w4v.w*h3v;
        acc5 += w5.x*h0v + w5.y*h1v + w5.z*h2v + w5.w*h3v;
      }
    }

    const float m1s = (t == 0) ? 0.f : 1.f;   // t=0: h-term lives in Q[0] via s0
    const float* qrow = Q + (size_t)(b * 128 + t) * 768 + d;
    float gi0 = fmaf(acc0, m1s, qrow[0]);
    float gi1 = fmaf(acc1, m1s, qrow[256]);
    float gi2 = fmaf(acc2, m1s, qrow[512]);
    float gh0 = acc3 + bh0, gh1 = acc4 + bh1, gh2 = acc5 + bh2;
    float r = 1.f / (1.f + expf(-(gi0 + gh0)));
    float z = 1.f / (1.f + expf(-(gi1 + gh1)));
    float nn = tanhf(gi2 + r * gh2);
    float hold = hl[d][bl];
    float hn = (1.f - z) * nn + z * hold;

    hglob[(size_t)((t + 1) & 1) * 16384 + d * 64 + b] = hn;
    out[(size_t)(b * 128 + t) * 3328 + d] = hn;

    // ---- grid barrier (all 64 blocks resident) ----
    __threadfence();
    __syncthreads();
    target += 64;
    if (tid == 0) {
      __hip_atomic_fetch_add(counter, 1u, __ATOMIC_ACQ_REL, __HIP_MEMORY_SCOPE_AGENT);
      while (__hip_atomic_load(counter, __ATOMIC_ACQUIRE, __HIP_MEMORY_SCOPE_AGENT) < target) {}
    }
    __syncthreads();
  }
}

// =====================================================================
// Host-side launch
// =====================================================================
static inline void launch_gemm(const float* A, int lda, const float* B, int ldb,
                               float* C, int ldc, int M, int N, int K,
                               const float* bias, const float* src, int ldsrc,
                               const float* scale_ptr, int relu, hipStream_t s)
{
  dim3 g(N / 64, M / 64);
  gemm_nt<<<g, 256, 0, s>>>(A, lda, B, ldb, C, ldc, K, bias, src, ldsrc, scale_ptr, relu);
}

extern "C" void kernel_launch(void* const* d_in, const int* in_sizes, int n_in,
                              void* d_out, int out_size, void* d_ws, size_t ws_size,
                              hipStream_t stream)
{
  (void)in_sizes; (void)n_in; (void)out_size;

  const float* emb_v   = (const float*)d_in[0];
  const float* emb_t   = (const float*)d_in[1];
  const float* emb_p   = (const float*)d_in[2];
  const float* noise   = (const float*)d_in[3];
  const float* h0      = (const float*)d_in[4];
  const float* s0      = (const float*)d_in[5];
  const float* pvw     = (const float*)d_in[6];
  const float* pvb     = (const float*)d_in[7];
  const float* ptw     = (const float*)d_in[8];
  const float* ptb     = (const float*)d_in[9];
  const float* ppw     = (const float*)d_in[10];
  const float* ppb     = (const float*)d_in[11];
  const float* aiw     = (const float*)d_in[12];
  const float* aib     = (const float*)d_in[13];
  const float* aow     = (const float*)d_in[14];
  const float* aob     = (const float*)d_in[15];
  const float* importance = (const float*)d_in[16];
  const float* fw1     = (const float*)d_in[17];
  const float* fb1     = (const float*)d_in[18];
  const float* fw2     = (const float*)d_in[19];
  const float* fb2     = (const float*)d_in[20];
  const float* ln_g    = (const float*)d_in[21];
  const float* ln_b    = (const float*)d_in[22];
  const float* gwih    = (const float*)d_in[23];
  const float* gwhh    = (const float*)d_in[24];
  const float* gbih    = (const float*)d_in[25];
  const float* gbhh    = (const float*)d_in[26];
  const float* prw     = (const float*)d_in[27];
  const float* prb     = (const float*)d_in[28];
  const float* pow_    = (const float*)d_in[29];
  const float* pob     = (const float*)d_in[30];

  float* out = (float*)d_out;
  float* ws  = (float*)d_ws;
  unsigned int* counter = (unsigned int*)d_ws;

  // ---------------- workspace layout (floats) ----------------
  size_t off = 64;  // counter region
  auto A_ = [&](size_t n) { size_t o = off; off += n; return o; };
  const size_t o_imp    = A_(4);
  const size_t o_rep    = A_(3072);
  const size_t o_bqkv   = A_(3 * 3072);
  const size_t o_bf1    = A_(1024);
  const size_t o_projTv = A_(512 * 1024);
  const size_t o_projTt = A_(512 * 1024);
  const size_t o_projTp = A_(256 * 1024);
  const size_t o_aoT    = A_(1024 * 1024);
  const size_t o_WphT   = A_(256 * 1024);
  const size_t o_Wqkv_v = A_(3072 * 512);
  const size_t o_Wqkv_t = A_(3072 * 512);
  const size_t o_Wqkv_p = A_(3072 * 256);
  const size_t o_Wf1    = A_(1024 * 3072);
  const size_t o_M1     = A_(768 * 256);
  const size_t o_fused  = A_(8192 * 1024);
  const size_t o_Fpb    = A_(8192 * 1024);
  const size_t o_hglob  = A_(2 * 16384);
  const size_t o_pool   = off;

  // pick chunk size by available workspace (phase-A/phase-B regions alias)
  int NC = 2048;
  {
    size_t phaseA = (size_t)NC * 9216 + (size_t)NC * 3072 + 8192ull * 1024;
    size_t phaseB = 8192ull * 768 * 2 + 8192ull * 1024;
    size_t pool = phaseA > phaseB ? phaseA : phaseB;
    if ((o_pool + pool) * 4 > ws_size) NC = 512;
  }
  const size_t o_qkvc   = o_pool;
  const size_t o_attc   = o_qkvc + (size_t)NC * 9216;
  const size_t o_fused1 = o_attc + (size_t)NC * 3072;
  const size_t o_Fgi    = o_pool;                       // aliases qkvc (dead)
  const size_t o_Q      = o_Fgi + 8192ull * 768;
  const size_t o_R      = o_Q + 8192ull * 768;          // aliases attc/fused1 (dead)

  // ---------------- pipeline ----------------
  hipMemsetAsync(d_ws, 0, 256, stream);  // barrier counter

  imp_rep_k<<<1, 256, 0, stream>>>(importance, aob, ws + o_imp, ws + o_rep);

  // transposes for NN->NT weight precompute
  transpose_k<<<dim3(16, 32), 256, 0, stream>>>(pvw, 512, ws + o_projTv, 1024);
  transpose_k<<<dim3(16, 32), 256, 0, stream>>>(ptw, 512, ws + o_projTt, 1024);
  transpose_k<<<dim3(8, 32), 256, 0, stream>>>(ppw, 256, ws + o_projTp, 1024);
  transpose_k<<<dim3(32, 32), 256, 0, stream>>>(aow, 1024, ws + o_aoT, 1024);
  transpose_k<<<dim3(8, 32), 256, 0, stream>>>(pow_, 1280, ws + o_WphT, 1024);

  // folded weights:  Wqkv_m = attn_in_w @ proj_w_m  (3072 x {512,512,256})
  launch_gemm(aiw, 1024, ws + o_projTv, 1024, ws + o_Wqkv_v, 512, 3072, 512, 1024,
              nullptr, nullptr, 0, nullptr, 0, stream);
  launch_gemm(aiw, 1024, ws + o_projTt, 1024, ws + o_Wqkv_t, 512, 3072, 512, 1024,
              nullptr, nullptr, 0, nullptr, 0, stream);
  launch_gemm(aiw, 1024, ws + o_projTp, 1024, ws + o_Wqkv_p, 256, 3072, 256, 1024,
              nullptr, nullptr, 0, nullptr, 0, stream);
  // Wf1[:, m*1024:...] = imp_m * fuse_w1_m @ attn_out_w
  for (int m = 0; m < 3; ++m)
    launch_gemm(fw1 + m * 1024, 3072, ws + o_aoT, 1024, ws + o_Wf1 + m * 1024, 3072,
                1024, 1024, 1024, nullptr, nullptr, 0, ws + o_imp + m, 0, stream);
  // M1 = W_ih_s @ Wpost_h  (768 x 256)
  launch_gemm(gwih, 2048, ws + o_WphT, 1024, ws + o_M1, 256, 768, 256, 1024,
              nullptr, nullptr, 0, nullptr, 0, stream);

  // folded biases
  matvec_nt<<<3072, 64, 0, stream>>>(aiw, 1024, pvb, aib, ws + o_bqkv + 0, 1024);
  matvec_nt<<<3072, 64, 0, stream>>>(aiw, 1024, ptb, aib, ws + o_bqkv + 3072, 1024);
  matvec_nt<<<3072, 64, 0, stream>>>(aiw, 1024, ppb, aib, ws + o_bqkv + 6144, 1024);
  matvec_nt<<<1024, 64, 0, stream>>>(fw1, 3072, ws + o_rep, fb1, ws + o_bf1, 3072);

  // phase A: qkv -> attention -> fused1 (chunked over N to bound ws)
  const int nchunk = 8192 / NC;
  for (int c = 0; c < nchunk; ++c) {
    launch_gemm(emb_v + (size_t)c * NC * 512, 512, ws + o_Wqkv_v, 512,
                ws + o_qkvc + 0, 9216, NC, 3072, 512, ws + o_bqkv + 0,
                nullptr, 0, nullptr, 0, stream);
    launch_gemm(emb_t + (size_t)c * NC * 512, 512, ws + o_Wqkv_t, 512,
                ws + o_qkvc + 3072, 9216, NC, 3072, 512, ws + o_bqkv + 3072,
                nullptr, 0, nullptr, 0, stream);
    launch_gemm(emb_p + (size_t)c * NC * 256, 256, ws + o_Wqkv_p, 256,
                ws + o_qkvc + 6144, 9216, NC, 3072, 256, ws + o_bqkv + 6144,
                nullptr, 0, nullptr, 0, stream);
    attn3<<<NC, 256, 0, stream>>>(ws + o_qkvc, ws + o_attc);
    launch_gemm(ws + o_attc, 3072, ws + o_Wf1, 3072,
                ws + o_fused1 + (size_t)c * NC * 1024, 1024, NC, 1024, 3072,
                ws + o_bf1, nullptr, 0, nullptr, 1 /*relu*/, stream);
  }

  // fuse2 + layernorm -> fused
  launch_gemm(ws + o_fused1, 1024, fw2, 1024, ws + o_fused, 1024, 8192, 1024, 1024,
              fb2, nullptr, 0, nullptr, 0, stream);
  layernorm_ip<<<8192, 256, 0, stream>>>(ws + o_fused, ln_g, ln_b);

  // phase B precomputes
  launch_gemm(ws + o_fused, 1024, gwih + 1024, 2048, ws + o_Fgi, 768, 8192, 768, 1024,
              nullptr, nullptr, 0, nullptr, 0, stream);
  launch_gemm(ws + o_fused, 1024, pow_ + 256, 1280, ws + o_Fpb, 1024, 8192, 1024, 1024,
              pob, nullptr, 0, nullptr, 0, stream);
  build_R_k<<<8192, 256, 0, stream>>>(ws + o_Fpb, noise, s0, ws + o_R);
  launch_gemm(ws + o_R, 1024, gwih, 2048, ws + o_Q, 768, 8192, 768, 1024,
              gbih, ws + o_Fgi, 768, nullptr, 0, stream);

  // sequential rollout
  copy_h0_k<<<64, 256, 0, stream>>>(h0, ws + o_hglob);
  rssm_recur<<<64, 256, 0, stream>>>(ws + o_M1, gwhh, gbhh, ws + o_Q,
                                     ws + o_hglob, out, counter);

  // deferred parallel outputs: prior, post, s_new
  launch_gemm(out, 3328, prw, 256, out + 1280, 3328, 8192, 1024, 256,
              prb, nullptr, 0, nullptr, 0, stream);
  launch_gemm(out, 3328, pow_, 1280, out + 2304, 3328, 8192, 1024, 256,
              nullptr, ws + o_Fpb, 1024, nullptr, 0, stream);
  s_out_k<<<8192, 256, 0, stream>>>(out, noise);
}

// Round 2
// 1900.588 us; speedup vs baseline: 3.9454x; 3.9454x over previous
//
#include <hip/hip_runtime.h>
#include <cstdint>
#include <cstddef>

#define F4(p)  (*(reinterpret_cast<float4*>(p)))
#define CF4(p) (*(reinterpret_cast<const float4*>(p)))

typedef __attribute__((ext_vector_type(8))) short short8;
typedef __attribute__((ext_vector_type(4))) float f32x4;

__device__ __forceinline__ float bf2f(unsigned short h) {
  return __uint_as_float(((unsigned int)h) << 16);
}
__device__ __forceinline__ unsigned short f2bf(float x) {
  unsigned int u = __float_as_uint(x);
  return (unsigned short)((u + 0x7FFFu + ((u >> 16) & 1u)) >> 16);
}

#if __has_builtin(__builtin_amdgcn_global_load_lds)
#define USE_GLL 1
#else
#define USE_GLL 0
#endif

// stage 16B: global (per-lane addr) -> LDS. With GLL: dest = wave-uniform base
// + lane*16 (hardware). Fallback: per-lane reg round-trip (same layout).
__device__ __forceinline__ void stage16(unsigned short* lds_lane,
                                        unsigned short* lds_wavebase,
                                        const unsigned short* g) {
#if USE_GLL
  __builtin_amdgcn_global_load_lds(
      (const __attribute__((address_space(1))) unsigned int*)g,
      (__attribute__((address_space(3))) unsigned int*)lds_wavebase, 16, 0, 0);
#else
  *(short8*)lds_lane = *(const short8*)g;
#endif
}

// =====================================================================
// Generic bf16 MFMA GEMM: C[M,N] = post( scale*(A@B^T) + bias + src )
// A:[M,K] bf16 (lda), optional dual-A (A for k<kSplit, A2 after),
// B:[N,K] bf16 (ldb), C f32 or bf16 (obf16). 128x128 tile, BK=64,
// 4 waves 2x2, XOR-swizzled LDS (unit ^= row&7) via pre-swizzled source.
// Requires M%128==0, N%128==0, K%64==0, lda/ldb%8==0.
// =====================================================================
__global__ __launch_bounds__(256) void gemm_bf(
    const unsigned short* __restrict__ A, int lda,
    const unsigned short* __restrict__ A2, int lda2, int kSplit,
    const unsigned short* __restrict__ B, int ldb,
    void* __restrict__ Cv, int ldc, int K,
    const float* __restrict__ bias,
    const float* __restrict__ src, int ldsrc,
    const float* __restrict__ scale_ptr, int relu, int obf16)
{
  __shared__ unsigned short As[128 * 64];
  __shared__ unsigned short Bs[128 * 64];
  const int tid = threadIdx.x;
  const int wv = tid >> 6, ln = tid & 63;
  const int wm = wv >> 1, wn = wv & 1;
  const size_t gm0 = (size_t)blockIdx.y * 128;
  const size_t gn0 = (size_t)blockIdx.x * 128;

  f32x4 acc[4][4];
  #pragma unroll
  for (int i = 0; i < 4; ++i)
    #pragma unroll
    for (int j = 0; j < 4; ++j) acc[i][j] = (f32x4){0.f, 0.f, 0.f, 0.f};

  for (int kk = 0; kk < K; kk += 64) {
    const unsigned short* Ause = A; int lduse = lda; int kkA = kk;
    if (A2 != nullptr && kk >= kSplit) { Ause = A2; lduse = lda2; kkA = kk - kSplit; }
    #pragma unroll
    for (int j = 0; j < 4; ++j) {
      int idx = j * 256 + tid;
      int r = idx >> 3, u = idx & 7;
      int ksw = (u ^ (r & 7)) << 3;
      const unsigned short* ga = Ause + (gm0 + r) * lduse + kkA + ksw;
      stage16(&As[idx * 8], &As[(idx & ~63) * 8], ga);
      const unsigned short* gb = B + (gn0 + r) * ldb + kk + ksw;
      stage16(&Bs[idx * 8], &Bs[(idx & ~63) * 8], gb);
    }
    __syncthreads();
    #pragma unroll
    for (int ks = 0; ks < 2; ++ks) {
      short8 af[4], bfv[4];
      #pragma unroll
      for (int mi = 0; mi < 4; ++mi) {
        int r = wm * 64 + mi * 16 + (ln & 15);
        int u = (ks * 4 + (ln >> 4)) ^ (r & 7);
        af[mi] = *(const short8*)&As[(r * 8 + u) * 8];
      }
      #pragma unroll
      for (int nj = 0; nj < 4; ++nj) {
        int r = wn * 64 + nj * 16 + (ln & 15);
        int u = (ks * 4 + (ln >> 4)) ^ (r & 7);
        bfv[nj] = *(const short8*)&Bs[(r * 8 + u) * 8];
      }
      #pragma unroll
      for (int mi = 0; mi < 4; ++mi)
        #pragma unroll
        for (int nj = 0; nj < 4; ++nj)
          acc[mi][nj] = __builtin_amdgcn_mfma_f32_16x16x32_bf16(
              af[mi], bfv[nj], acc[mi][nj], 0, 0, 0);
    }
    __syncthreads();
  }

  float sc = scale_ptr ? *scale_ptr : 1.0f;
  #pragma unroll
  for (int nj = 0; nj < 4; ++nj) {
    size_t gc = gn0 + wn * 64 + nj * 16 + (ln & 15);
    float bv = bias ? bias[gc] : 0.f;
    #pragma unroll
    for (int mi = 0; mi < 4; ++mi) {
      #pragma unroll
      for (int q = 0; q < 4; ++q) {
        size_t gr = gm0 + wm * 64 + mi * 16 + ((ln >> 4) << 2) + q;
        float v = acc[mi][nj][q] * sc + bv;
        if (src) v += src[gr * (size_t)ldsrc + gc];
        if (relu) v = fmaxf(v, 0.f);
        if (obf16) ((unsigned short*)Cv)[gr * (size_t)ldc + gc] = f2bf(v);
        else       ((float*)Cv)[gr * (size_t)ldc + gc] = v;
      }
    }
  }
}

// =====================================================================
// fp32 -> bf16 conversion (vector x4)
// =====================================================================
__global__ __launch_bounds__(256) void cvt_bf(
    const float* __restrict__ in, unsigned short* __restrict__ outp, int n4)
{
  int i = blockIdx.x * 256 + threadIdx.x;
  if (i < n4) {
    float4 v = CF4(in + (size_t)i * 4);
    ushort4 o;
    o.x = f2bf(v.x); o.y = f2bf(v.y); o.z = f2bf(v.z); o.w = f2bf(v.w);
    *(ushort4*)(outp + (size_t)i * 4) = o;
  }
}

// =====================================================================
// Transpose f32 in (R x Cc, ldin) -> bf16 out (Cc x R)
// =====================================================================
__global__ __launch_bounds__(256) void transpose_bf(
    const float* __restrict__ in, int ldin, unsigned short* __restrict__ outp, int R)
{
  __shared__ float tile[32][33];
  int c0 = blockIdx.x * 32, r0 = blockIdx.y * 32;
  int tx = threadIdx.x & 31, ty = threadIdx.x >> 5;
  #pragma unroll
  for (int i = ty; i < 32; i += 8)
    tile[i][tx] = in[(size_t)(r0 + i) * ldin + c0 + tx];
  __syncthreads();
  #pragma unroll
  for (int i = ty; i < 32; i += 8)
    outp[(size_t)(c0 + i) * R + r0 + tx] = f2bf(tile[tx][i]);
}

// =====================================================================
// matvec: out[i] = dot(A[i,:K], x) + badd[i]  (f32)
// =====================================================================
__global__ __launch_bounds__(64) void matvec_nt(
    const float* __restrict__ A, int lda,
    const float* __restrict__ x, const float* __restrict__ badd,
    float* __restrict__ outp, int K)
{
  int i = blockIdx.x, t = threadIdx.x;
  const float* Ar = A + (size_t)i * lda;
  float s = 0.f;
  for (int k = t * 4; k < K; k += 256) {
    float4 a = CF4(Ar + k);
    float4 xx = CF4(x + k);
    s += a.x * xx.x + a.y * xx.y + a.z * xx.z + a.w * xx.w;
  }
  #pragma unroll
  for (int m = 32; m > 0; m >>= 1) s += __shfl_xor(s, m);
  if (t == 0) outp[i] = s + (badd ? badd[i] : 0.f);
}

// =====================================================================
// importance softmax + rep vector
// =====================================================================
__global__ __launch_bounds__(256) void imp_rep_k(
    const float* __restrict__ importance, const float* __restrict__ aob,
    float* __restrict__ imp, float* __restrict__ rep)
{
  __shared__ float si[3];
  if (threadIdx.x == 0) {
    float a = importance[0], b = importance[1], c = importance[2];
    float mx = fmaxf(a, fmaxf(b, c));
    float ea = expf(a - mx), eb = expf(b - mx), ec = expf(c - mx);
    float inv = 1.f / (ea + eb + ec);
    si[0] = ea * inv; si[1] = eb * inv; si[2] = ec * inv;
    imp[0] = si[0]; imp[1] = si[1]; imp[2] = si[2];
  }
  __syncthreads();
  for (int idx = threadIdx.x; idx < 3072; idx += 256)
    rep[idx] = si[idx >> 10] * aob[idx & 1023];
}

// =====================================================================
// 3-token MHA, f32 in -> bf16 out
// =====================================================================
__global__ __launch_bounds__(256) void attn3(
    const float* __restrict__ qkv, unsigned short* __restrict__ att)
{
  const int n = blockIdx.x;
  const float* row = qkv + (size_t)n * 9216;
  __shared__ float qk[6144];
  __shared__ float sc[72];
  __shared__ float pw[72];
  const int t = threadIdx.x;
  for (int idx = t; idx < 1536; idx += 256) {
    int m = idx >> 8;
    int off = (idx & 255) << 2;
    const float* srcp = (m < 3) ? (row + m * 3072 + off)
                                : (row + (m - 3) * 3072 + 1024 + off);
    F4(&qk[m * 1024 + off]) = CF4(srcp);
  }
  __syncthreads();
  if (t < 72) {
    int h = t / 9, i = (t % 9) / 3, j = t % 3;
    const float* qp = &qk[i * 1024 + h * 128];
    const float* kp = &qk[3072 + j * 1024 + h * 128];
    float s = 0.f;
    int rot = (t & 31) * 4;
    for (int d2 = 0; d2 < 128; ++d2) {
      int dx = (d2 + rot) & 127;
      s += qp[dx] * kp[dx];
    }
    sc[t] = s * 0.08838834764831845f;
  }
  __syncthreads();
  if (t < 24) {
    int base = t * 3;
    float a = sc[base], b = sc[base + 1], c = sc[base + 2];
    float mx = fmaxf(a, fmaxf(b, c));
    float ea = expf(a - mx), eb = expf(b - mx), ec = expf(c - mx);
    float inv = 1.f / (ea + eb + ec);
    pw[base] = ea * inv; pw[base + 1] = eb * inv; pw[base + 2] = ec * inv;
  }
  __syncthreads();
  unsigned short* outp = att + (size_t)n * 3072;
  #pragma unroll
  for (int rep = 0; rep < 3; ++rep) {
    int idx = (rep * 256 + t) << 2;
    int i = idx >> 10;
    int hd = idx & 1023;
    int h = hd >> 7;
    int pb = (h * 3 + i) * 3;
    float w0 = pw[pb], w1 = pw[pb + 1], w2 = pw[pb + 2];
    float4 v0 = CF4(row + 2048 + hd);
    float4 v1 = CF4(row + 3072 + 2048 + hd);
    float4 v2 = CF4(row + 6144 + 2048 + hd);
    ushort4 o;
    o.x = f2bf(w0 * v0.x + w1 * v1.x + w2 * v2.x);
    o.y = f2bf(w0 * v0.y + w1 * v1.y + w2 * v2.y);
    o.z = f2bf(w0 * v0.z + w1 * v1.z + w2 * v2.z);
    o.w = f2bf(w0 * v0.w + w1 * v1.w + w2 * v2.w);
    *(ushort4*)(outp + idx) = o;
  }
}

// =====================================================================
// LayerNorm in-place on bf16 rows of 1024 (stats in f32)
// =====================================================================
__global__ __launch_bounds__(256) void layernorm_bf(
    unsigned short* __restrict__ X, const float* __restrict__ g,
    const float* __restrict__ bta)
{
  int n = blockIdx.x, t = threadIdx.x;
  unsigned short* row = X + (size_t)n * 1024;
  ushort4 hv = *(ushort4*)(row + t * 4);
  float x0 = bf2f(hv.x), x1 = bf2f(hv.y), x2 = bf2f(hv.z), x3 = bf2f(hv.w);
  float s = x0 + x1 + x2 + x3;
  float ss = x0 * x0 + x1 * x1 + x2 * x2 + x3 * x3;
  #pragma unroll
  for (int m = 32; m > 0; m >>= 1) { s += __shfl_xor(s, m); ss += __shfl_xor(ss, m); }
  __shared__ float rs[4], rss[4];
  int w = t >> 6;
  if ((t & 63) == 0) { rs[w] = s; rss[w] = ss; }
  __syncthreads();
  s = rs[0] + rs[1] + rs[2] + rs[3];
  ss = rss[0] + rss[1] + rss[2] + rss[3];
  float mean = s * (1.0f / 1024.0f);
  float var = ss * (1.0f / 1024.0f) - mean * mean;
  float inv = 1.0f / sqrtf(var + 1e-5f);
  float4 gg = CF4(g + t * 4);
  float4 bb = CF4(bta + t * 4);
  ushort4 o;
  o.x = f2bf((x0 - mean) * inv * gg.x + bb.x);
  o.y = f2bf((x1 - mean) * inv * gg.y + bb.y);
  o.z = f2bf((x2 - mean) * inv * gg.z + bb.z);
  o.w = f2bf((x3 - mean) * inv * gg.w + bb.w);
  *(ushort4*)(row + t * 4) = o;
}

// =====================================================================
// R[n] = (t==0) ? s0[b] : Fpb[n-1] + noise[n-1]   -> bf16
// =====================================================================
__global__ __launch_bounds__(256) void build_R_bf(
    const float* __restrict__ Fpb, const float* __restrict__ noise,
    const float* __restrict__ s0, unsigned short* __restrict__ R)
{
  size_t idx = (size_t)blockIdx.x * 256 + threadIdx.x;
  int n = (int)(idx >> 8);
  int k4 = (int)(idx & 255) << 2;
  float4 v;
  if ((n & 127) == 0) {
    v = CF4(s0 + (size_t)(n >> 7) * 1024 + k4);
  } else {
    float4 f = CF4(Fpb + (size_t)(n - 1) * 1024 + k4);
    float4 z = CF4(noise + (size_t)(n - 1) * 1024 + k4);
    v.x = f.x + z.x; v.y = f.y + z.y; v.z = f.z + z.z; v.w = f.w + z.w;
  }
  ushort4 o;
  o.x = f2bf(v.x); o.y = f2bf(v.y); o.z = f2bf(v.z); o.w = f2bf(v.w);
  *(ushort4*)(R + (size_t)n * 1024 + k4) = o;
}

// =====================================================================
// s_new = post + noise  (f32, out cols [256,1280) from [2304,3328))
// =====================================================================
__global__ __launch_bounds__(256) void s_out_k(
    float* __restrict__ outp, const float* __restrict__ noise)
{
  size_t idx = (size_t)blockIdx.x * 256 + threadIdx.x;
  int n = (int)(idx >> 8);
  int j4 = (int)(idx & 255) << 2;
  float4 p = CF4(outp + (size_t)n * 3328 + 2304 + j4);
  float4 z = CF4(noise + (size_t)n * 1024 + j4);
  float4 o; o.x = p.x + z.x; o.y = p.y + z.y; o.z = p.z + z.z; o.w = p.w + z.w;
  F4(outp + (size_t)n * 3328 + 256 + j4) = o;
}

// =====================================================================
// Arrange recurrence weights into per-block MFMA B-fragment order:
// Wr[dd][g][kt][lane][j] = W_g[(g%3)*256 + dd*16+(lane&15)][kt*32+(lane>>4)*8+j]
// where W = M1 (g<3) else Whh. Inputs already bf16.
// =====================================================================
__global__ __launch_bounds__(256) void wr_prep(
    const unsigned short* __restrict__ M1bf, const unsigned short* __restrict__ Whhbf,
    unsigned short* __restrict__ Wr)
{
  int idx = blockIdx.x * 256 + threadIdx.x;   // < 393216
  int j = idx & 7, l = (idx >> 3) & 63, kt = (idx >> 9) & 7;
  int rest = idx >> 12;                        // dd*6 + g
  int g = rest % 6, dd = rest / 6;
  int d = dd * 16 + (l & 15);
  int k = kt * 32 + ((l >> 4) << 3) + j;
  int srow = (g % 3) * 256 + d;
  const unsigned short* srcp = (g < 3) ? M1bf : Whhbf;
  Wr[idx] = srcp[(size_t)srow * 256 + k];
}

// =====================================================================
// h0 (f32 [64][256]) -> hist[0] A-fragment order:
// hist[0][w][kt][lane][j] = bf16(h0[16w+(lane&15)][kt*32+(lane>>4)*8+j])
// =====================================================================
__global__ __launch_bounds__(256) void h0_prep(
    const float* __restrict__ h0, unsigned short* __restrict__ hist)
{
  int idx = blockIdx.x * 256 + threadIdx.x;   // < 16384
  int j = idx & 7, l = (idx >> 3) & 63, kt = (idx >> 9) & 7, w = idx >> 12;
  int b = 16 * w + (l & 15);
  int k = kt * 32 + ((l >> 4) << 3) + j;
  hist[idx] = f2bf(h0[(size_t)b * 256 + k]);
}

// =====================================================================
// Sequential RSSM, weight-stationary MFMA. 16 blocks (one per 16-d slice),
// 256 threads = 4 waves (one per 16-b tile). Weights (6 gates x 16 d x 256 k)
// persistent in LDS as MFMA B-frags (48KB, conflict-free ds_read_b128).
// Per step: stage 32KB h-frags, 48 MFMA/wave, GRU, write hist[t+1]+Hrow,
// 16-block atomic grid barrier (all co-resident).
// =====================================================================
__global__ __launch_bounds__(256) void rssm_recur2(
    const unsigned short* __restrict__ Wr, const float* __restrict__ Q,
    const float* __restrict__ bhh, unsigned short* __restrict__ hist,
    unsigned short* __restrict__ Hrow, unsigned int* __restrict__ counter)
{
  const int dd = blockIdx.x;          // 0..15
  const int tid = threadIdx.x;
  const int w = tid >> 6, l = tid & 63;
  __shared__ unsigned short Wl[6 * 8 * 64 * 8];   // 48KB
  __shared__ unsigned short hA[4 * 8 * 64 * 8];   // 32KB

  // stage weights once
  const unsigned short* wsrc = Wr + (size_t)dd * 24576;
  #pragma unroll
  for (int j = 0; j < 12; ++j) {
    int idx = j * 256 + tid;
    stage16(&Wl[idx * 8], &Wl[(idx & ~63) * 8], wsrc + (size_t)idx * 8);
  }
  const int d = dd * 16 + (l & 15);
  const float bh0 = bhh[d], bh1 = bhh[256 + d], bh2 = bhh[512 + d];
  __syncthreads();

  unsigned int target = 0;
  for (int t = 0; t < 128; ++t) {
    // stage hist[t] (32KB, linear frag layout)
    const unsigned short* hsrc = hist + (size_t)t * 16384;
    #pragma unroll
    for (int j = 0; j < 8; ++j) {
      int idx = j * 256 + tid;
      stage16(&hA[idx * 8], &hA[(idx & ~63) * 8], hsrc + (size_t)idx * 8);
    }
    // prefetch Q values for this lane's 4 (b,d) cells
    float qv[3][4];
    #pragma unroll
    for (int i = 0; i < 4; ++i) {
      int b = w * 16 + ((l >> 4) << 2) + i;
      const float* qp = Q + (size_t)(b * 128 + t) * 768 + d;
      qv[0][i] = qp[0]; qv[1][i] = qp[256]; qv[2][i] = qp[512];
    }
    __syncthreads();   // hA ready (drains vmcnt)

    short8 a[8];
    #pragma unroll
    for (int kt = 0; kt < 8; ++kt)
      a[kt] = *(const short8*)&hA[((w * 8 + kt) * 64 + l) * 8];

    f32x4 acc[6];
    #pragma unroll
    for (int g = 0; g < 6; ++g) {
      f32x4 c = (f32x4){0.f, 0.f, 0.f, 0.f};
      #pragma unroll
      for (int kt = 0; kt < 8; ++kt) {
        short8 bfr = *(const short8*)&Wl[((g * 8 + kt) * 64 + l) * 8];
        c = __builtin_amdgcn_mfma_f32_16x16x32_bf16(a[kt], bfr, c, 0, 0, 0);
      }
      acc[g] = c;
    }

    const float m1s = (t == 0) ? 0.f : 1.f;  // t=0: s-term fully inside Q
    unsigned short* hdst = hist + (size_t)(t + 1) * 16384;
    const int kt_d = d >> 5;
    const int lp_hi = ((d >> 3) & 3) << 4;
    #pragma unroll
    for (int i = 0; i < 4; ++i) {
      int b = w * 16 + ((l >> 4) << 2) + i;
      float gi0 = fmaf(acc[0][i], m1s, qv[0][i]);
      float gi1 = fmaf(acc[1][i], m1s, qv[1][i]);
      float gi2 = fmaf(acc[2][i], m1s, qv[2][i]);
      float gh0 = acc[3][i] + bh0;
      float gh1 = acc[4][i] + bh1;
      float gh2 = acc[5][i] + bh2;
      float r = 1.f / (1.f + expf(-(gi0 + gh0)));
      float z = 1.f / (1.f + expf(-(gi1 + gh1)));
      float nn = tanhf(gi2 + r * gh2);
      int lp = lp_hi + (b & 15);
      size_t fidx = (size_t)((w * 8 + kt_d) * 64 + lp) * 8 + (d & 7);
      float hold = bf2f(hA[fidx]);
      float hn = (1.f - z) * nn + z * hold;
      unsigned short hb = f2bf(hn);
      hdst[fidx] = hb;
      Hrow[(size_t)(b * 128 + t) * 256 + d] = hb;
    }

    if (t < 127) {
      __threadfence();
      __syncthreads();
      target += 16;
      if (tid == 0) {
        __hip_atomic_fetch_add(counter, 1u, __ATOMIC_ACQ_REL, __HIP_MEMORY_SCOPE_AGENT);
        while (__hip_atomic_load(counter, __ATOMIC_ACQUIRE, __HIP_MEMORY_SCOPE_AGENT) < target) {}
      }
      __syncthreads();
      __threadfence();
    }
  }
}

// =====================================================================
// out[n][0:256] = f32(Hrow[n][:])
// =====================================================================
__global__ __launch_bounds__(256) void hrow_out(
    const unsigned short* __restrict__ Hrow, float* __restrict__ outp)
{
  int n = blockIdx.x, t = threadIdx.x;
  outp[(size_t)n * 3328 + t] = bf2f(Hrow[(size_t)n * 256 + t]);
}

// =====================================================================
// Host side
// =====================================================================
static inline void g_bf(const unsigned short* A, int lda,
                        const unsigned short* B, int ldb,
                        void* C, int ldc, int M, int N, int K,
                        const float* bias, const float* src, int ldsrc,
                        const float* scale, int relu, int obf16, hipStream_t s,
                        const unsigned short* A2 = nullptr, int lda2 = 0,
                        int kSplit = 1 << 30)
{
  dim3 grid(N / 128, M / 128);
  gemm_bf<<<grid, 256, 0, s>>>(A, lda, A2, lda2, kSplit, B, ldb, C, ldc, K,
                               bias, src, ldsrc, scale, relu, obf16);
}

extern "C" void kernel_launch(void* const* d_in, const int* in_sizes, int n_in,
                              void* d_out, int out_size, void* d_ws, size_t ws_size,
                              hipStream_t stream)
{
  (void)in_sizes; (void)n_in; (void)out_size;

  const float* emb_v = (const float*)d_in[0];
  const float* emb_t = (const float*)d_in[1];
  const float* emb_p = (const float*)d_in[2];
  const float* noise = (const float*)d_in[3];
  const float* h0    = (const float*)d_in[4];
  const float* s0    = (const float*)d_in[5];
  const float* pvw   = (const float*)d_in[6];
  const float* pvb   = (const float*)d_in[7];
  const float* ptw   = (const float*)d_in[8];
  const float* ptb   = (const float*)d_in[9];
  const float* ppw   = (const float*)d_in[10];
  const float* ppb   = (const float*)d_in[11];
  const float* aiw   = (const float*)d_in[12];
  const float* aib   = (const float*)d_in[13];
  const float* aow   = (const float*)d_in[14];
  const float* aob   = (const float*)d_in[15];
  const float* importance = (const float*)d_in[16];
  const float* fw1   = (const float*)d_in[17];
  const float* fb1   = (const float*)d_in[18];
  const float* fw2   = (const float*)d_in[19];
  const float* fb2   = (const float*)d_in[20];
  const float* ln_g  = (const float*)d_in[21];
  const float* ln_b  = (const float*)d_in[22];
  const float* gwih  = (const float*)d_in[23];
  const float* gwhh  = (const float*)d_in[24];
  const float* gbih  = (const float*)d_in[25];
  const float* gbhh  = (const float*)d_in[26];
  const float* prw   = (const float*)d_in[27];
  const float* prb   = (const float*)d_in[28];
  const float* pow_  = (const float*)d_in[29];
  const float* pob   = (const float*)d_in[30];

  float* out = (float*)d_out;
  char* W = (char*)d_ws;

  // ---- byte allocator ----
  size_t off = 0;
  auto alloc = [&](size_t bytes) { off = (off + 63) & ~63ull; size_t o = off; off += bytes; return o; };
  const size_t o_cnt    = alloc(256);
  const size_t o_imp    = alloc(16);
  const size_t o_rep    = alloc(3072 * 4);
  const size_t o_bqkv   = alloc(9216 * 4);
  const size_t o_bf1    = alloc(1024 * 4);
  const size_t o_gwihb  = alloc(768ull * 2048 * 2);
  const size_t o_whhb   = alloc(768ull * 256 * 2);
  const size_t o_m1b    = alloc(768ull * 256 * 2);
  const size_t o_prwb   = alloc(1024ull * 256 * 2);
  const size_t o_powb   = alloc(1024ull * 1280 * 2);
  const size_t o_wr     = alloc(16ull * 6 * 8 * 64 * 8 * 2);
  const size_t o_hist   = alloc(129ull * 16384 * 2);
  const size_t o_hrow   = alloc(8192ull * 256 * 2);
  const size_t o_fusedb = alloc(8192ull * 1024 * 2);
  const size_t o_fpb    = alloc(8192ull * 1024 * 4);
  const size_t o_rbf    = alloc(8192ull * 1024 * 2);
  const size_t o_embvb  = alloc(8192ull * 512 * 2);
  const size_t o_embtb  = alloc(8192ull * 512 * 2);
  const size_t o_embpb  = alloc(8192ull * 256 * 2);
  const size_t o_wqv    = alloc(3072ull * 512 * 2);
  const size_t o_wqt    = alloc(3072ull * 512 * 2);
  const size_t o_wqp    = alloc(3072ull * 256 * 2);
  const size_t o_wf1    = alloc(1024ull * 3072 * 2);
  const size_t o_fw2b   = alloc(1024ull * 1024 * 2);
  const size_t o_fused1 = alloc(8192ull * 1024 * 2);
  const size_t o_sub    = (off + 63) & ~63ull;

  // sub-pool (time-shared): prep temps -> per-chunk qkv/att -> Q
  const size_t so_aiwb  = 0;
  const size_t so_fw1b  = so_aiwb + 3072ull * 1024 * 2;
  const size_t so_pTv   = so_fw1b + 1024ull * 3072 * 2;
  const size_t so_pTt   = so_pTv + 512ull * 1024 * 2;
  const size_t so_pTp   = so_pTt + 512ull * 1024 * 2;
  const size_t so_aoT   = so_pTp + 256ull * 1024 * 2;
  const size_t so_WphT  = so_aoT + 1024ull * 1024 * 2;
  const size_t prep_bytes = so_WphT + 256ull * 1024 * 2;
  const size_t q_bytes = 8192ull * 768 * 4;
  auto chunk_bytes = [](long nc) { return (size_t)nc * 9216 * 4 + (size_t)nc * 3072 * 2; };

  int NC = 2048;
  {
    size_t sub = prep_bytes > q_bytes ? prep_bytes : q_bytes;
    size_t cb = chunk_bytes(NC);
    if (cb > sub) sub = cb;
    if (o_sub + sub > ws_size) NC = 512;
  }
  const size_t o_qkvc = o_sub;
  const size_t o_attc = o_sub + (size_t)NC * 9216 * 4;
  const size_t o_q    = o_sub;

  auto FP = [&](size_t o) { return (float*)(W + o); };
  auto UP = [&](size_t o) { return (unsigned short*)(W + o); };

  // ---- pipeline ----
  hipMemsetAsync(W + o_cnt, 0, 256, stream);
  imp_rep_k<<<1, 256, 0, stream>>>(importance, aob, FP(o_imp), FP(o_rep));

  // bf16 conversions of weights / inputs
  auto cvt = [&](const float* in, unsigned short* op, size_t n) {
    int n4 = (int)(n / 4);
    cvt_bf<<<(n4 + 255) / 256, 256, 0, stream>>>(in, op, n4);
  };
  cvt(aiw,  UP(o_sub + so_aiwb), 3072ull * 1024);
  cvt(fw1,  UP(o_sub + so_fw1b), 1024ull * 3072);
  cvt(fw2,  UP(o_fw2b), 1024ull * 1024);
  cvt(gwih, UP(o_gwihb), 768ull * 2048);
  cvt(gwhh, UP(o_whhb), 768ull * 256);
  cvt(prw,  UP(o_prwb), 1024ull * 256);
  cvt(pow_, UP(o_powb), 1024ull * 1280);
  cvt(emb_v, UP(o_embvb), 8192ull * 512);
  cvt(emb_t, UP(o_embtb), 8192ull * 512);
  cvt(emb_p, UP(o_embpb), 8192ull * 256);

  // transposes (f32 -> bf16)
  transpose_bf<<<dim3(16, 32), 256, 0, stream>>>(pvw, 512, UP(o_sub + so_pTv), 1024);
  transpose_bf<<<dim3(16, 32), 256, 0, stream>>>(ptw, 512, UP(o_sub + so_pTt), 1024);
  transpose_bf<<<dim3(8, 32), 256, 0, stream>>>(ppw, 256, UP(o_sub + so_pTp), 1024);
  transpose_bf<<<dim3(32, 32), 256, 0, stream>>>(aow, 1024, UP(o_sub + so_aoT), 1024);
  transpose_bf<<<dim3(8, 32), 256, 0, stream>>>(pow_, 1280, UP(o_sub + so_WphT), 1024);

  // folded biases (f32)
  matvec_nt<<<3072, 64, 0, stream>>>(aiw, 1024, pvb, aib, FP(o_bqkv) + 0, 1024);
  matvec_nt<<<3072, 64, 0, stream>>>(aiw, 1024, ptb, aib, FP(o_bqkv) + 3072, 1024);
  matvec_nt<<<3072, 64, 0, stream>>>(aiw, 1024, ppb, aib, FP(o_bqkv) + 6144, 1024);
  matvec_nt<<<1024, 64, 0, stream>>>(fw1, 3072, FP(o_rep), fb1, FP(o_bf1), 3072);

  // folded weights (bf16 MFMA, bf16 out)
  g_bf(UP(o_sub + so_aiwb), 1024, UP(o_sub + so_pTv), 1024, UP(o_wqv), 512,
       3072, 512, 1024, nullptr, nullptr, 0, nullptr, 0, 1, stream);
  g_bf(UP(o_sub + so_aiwb), 1024, UP(o_sub + so_pTt), 1024, UP(o_wqt), 512,
       3072, 512, 1024, nullptr, nullptr, 0, nullptr, 0, 1, stream);
  g_bf(UP(o_sub + so_aiwb), 1024, UP(o_sub + so_pTp), 1024, UP(o_wqp), 256,
       3072, 256, 1024, nullptr, nullptr, 0, nullptr, 0, 1, stream);
  for (int m = 0; m < 3; ++m)
    g_bf(UP(o_sub + so_fw1b) + m * 1024, 3072, UP(o_sub + so_aoT), 1024,
         UP(o_wf1) + m * 1024, 3072, 1024, 1024, 1024,
         nullptr, nullptr, 0, FP(o_imp) + m, 0, 1, stream);
  g_bf(UP(o_gwihb), 2048, UP(o_sub + so_WphT), 1024, UP(o_m1b), 256,
       768, 256, 1024, nullptr, nullptr, 0, nullptr, 0, 1, stream);

  // recurrence weight/h0 prep
  wr_prep<<<1536, 256, 0, stream>>>(UP(o_m1b), UP(o_whhb), UP(o_wr));
  h0_prep<<<64, 256, 0, stream>>>(h0, UP(o_hist));

  // phase A: qkv -> attention -> fused1 (chunked)
  const int nchunk = 8192 / NC;
  for (int c = 0; c < nchunk; ++c) {
    g_bf(UP(o_embvb) + (size_t)c * NC * 512, 512, UP(o_wqv), 512,
         FP(o_qkvc) + 0, 9216, NC, 3072, 512, FP(o_bqkv) + 0,
         nullptr, 0, nullptr, 0, 0, stream);
    g_bf(UP(o_embtb) + (size_t)c * NC * 512, 512, UP(o_wqt), 512,
         FP(o_qkvc) + 3072, 9216, NC, 3072, 512, FP(o_bqkv) + 3072,
         nullptr, 0, nullptr, 0, 0, stream);
    g_bf(UP(o_embpb) + (size_t)c * NC * 256, 256, UP(o_wqp), 256,
         FP(o_qkvc) + 6144, 9216, NC, 3072, 256, FP(o_bqkv) + 6144,
         nullptr, 0, nullptr, 0, 0, stream);
    attn3<<<NC, 256, 0, stream>>>(FP(o_qkvc), UP(o_attc));
    g_bf(UP(o_attc), 3072, UP(o_wf1), 3072,
         UP(o_fused1) + (size_t)c * NC * 1024, 1024, NC, 1024, 3072,
         FP(o_bf1), nullptr, 0, nullptr, 1 /*relu*/, 1, stream);
  }

  // fuse2 (bf16 out) + LN in place
  g_bf(UP(o_fused1), 1024, UP(o_fw2b), 1024, UP(o_fusedb), 1024,
       8192, 1024, 1024, fb2, nullptr, 0, nullptr, 0, 1, stream);
  layernorm_bf<<<8192, 256, 0, stream>>>(UP(o_fusedb), ln_g, ln_b);

  // Fpb = fused @ pow[:,256:]^T + pob   (f32)
  g_bf(UP(o_fusedb), 1024, UP(o_powb) + 256, 1280, FP(o_fpb), 1024,
       8192, 1024, 1024, pob, nullptr, 0, nullptr, 0, 0, stream);
  // R (bf16)
  build_R_bf<<<8192, 256, 0, stream>>>(FP(o_fpb), noise, s0, UP(o_rbf));
  // Q = [R | fused] @ gwih^T + gbih  (dual-A, K=2048, f32 out)
  g_bf(UP(o_rbf), 1024, UP(o_gwihb), 2048, FP(o_q), 768,
       8192, 768, 2048, gbih, nullptr, 0, nullptr, 0, 0, stream,
       UP(o_fusedb), 1024, 1024);

  // sequential rollout
  rssm_recur2<<<16, 256, 0, stream>>>(UP(o_wr), FP(o_q), gbhh, UP(o_hist),
                                      UP(o_hrow), (unsigned int*)(W + o_cnt));

  // outputs
  hrow_out<<<8192, 256, 0, stream>>>(UP(o_hrow), out);
  g_bf(UP(o_hrow), 256, UP(o_prwb), 256, out + 1280, 3328,
       8192, 1024, 256, prb, nullptr, 0, nullptr, 0, 0, stream);
  g_bf(UP(o_hrow), 256, UP(o_powb), 1280, out + 2304, 3328,
       8192, 1024, 256, nullptr, FP(o_fpb), 1024, nullptr, 0, 0, stream);
  s_out_k<<<8192, 256, 0, stream>>>(out, noise);
}